// Round 9
// baseline (217.099 us; speedup 1.0000x reference)
//
#include <hip/hip_runtime.h>

#define HID 64
#define IN_DIM 128
#define R_DEG 4
#define R_ACC 8
#define JT 16            // j-tile width
#define NT (HID / JT)    // 4 tiles

// ---------------- deg histogram: full grid, 4 edges/thread, 4 replicas ----------------
__global__ __launch_bounds__(256) void k_deg(const int* __restrict__ dst,
                                             int* __restrict__ degR, int E, int Npad) {
    int* deg = degR + (size_t)(blockIdx.x & (R_DEG - 1)) * Npad;
    int t = blockIdx.x * blockDim.x + threadIdx.x;
    int e = t * 4;
    if (e + 3 < E) {
        int4 d4 = *(const int4*)(dst + e);
        atomicAdd(&deg[d4.x], 1);
        atomicAdd(&deg[d4.y], 1);
        atomicAdd(&deg[d4.z], 1);
        atomicAdd(&deg[d4.w], 1);
    } else {
        for (; e < E; ++e) atomicAdd(&deg[dst[e]], 1);
    }
}

// ---------------- dense: thread-per-node, j-tiled (4 x 16 acc), no LDS W tile ----------------
// z[node] = relu(x@W_in + b_in) . w_eff,  w_eff = W_g @ W_out (computed per block in LDS)
__global__ __launch_bounds__(256) void k_dense(const float* __restrict__ x,
                                               const float* __restrict__ W_in,
                                               const float* __restrict__ b_in,
                                               const float* __restrict__ W_g,
                                               const float* __restrict__ W_out,
                                               float* __restrict__ z, int N) {
    __shared__ float weff_l[HID];
    if (threadIdx.x < HID) {
        float s = 0.0f;
#pragma unroll
        for (int jp = 0; jp < HID; ++jp)
            s = fmaf(W_g[threadIdx.x * HID + jp], W_out[jp], s);
        weff_l[threadIdx.x] = s;
    }
    __syncthreads();

    int node = blockIdx.x * 256 + threadIdx.x;
    if (node >= N) node = N - 1;   // clamped threads duplicate-write identical values

    const float4* xrow = (const float4*)(x + (size_t)node * IN_DIM);
    float zv = 0.0f;

#pragma unroll
    for (int t = 0; t < NT; ++t) {           // j-tile: 16 accumulators live at a time
        float acc[JT];
#pragma unroll
        for (int jj = 0; jj < JT; ++jj)
            acc[jj] = b_in[t * JT + jj];     // uniform -> s_load

        for (int k4 = 0; k4 < IN_DIM / 4; ++k4) {
            float4 xv = xrow[k4];            // per-lane, L1/L2-resident on re-reads
            const float xk[4] = {xv.x, xv.y, xv.z, xv.w};
#pragma unroll
            for (int kk = 0; kk < 4; ++kk) {
                const float* wr = W_in + (k4 * 4 + kk) * HID + t * JT;  // wave-uniform
#pragma unroll
                for (int jj = 0; jj < JT; ++jj)
                    acc[jj] = fmaf(xk[kk], wr[jj], acc[jj]);
            }
        }
#pragma unroll
        for (int jj = 0; jj < JT; ++jj)
            zv = fmaf(fmaxf(acc[jj], 0.0f), weff_l[t * JT + jj], zv);
    }
    z[node] = zv;
}

// ---------------- dinv + seed: dinv=rsqrt(deg+1); zs=z*dinv; accR[0]=zs; accR[1..7]=0 ----
__global__ __launch_bounds__(256) void k_dinv(const int* __restrict__ degR,
                                              const float* __restrict__ z,
                                              float* __restrict__ dinv,
                                              float* __restrict__ zs,
                                              float* __restrict__ accR,
                                              int N, int Npad) {
    int i = blockIdx.x * blockDim.x + threadIdx.x;
    if (i >= N) return;
    int d = 0;
#pragma unroll
    for (int r = 0; r < R_DEG; ++r) d += degR[(size_t)r * Npad + i];
    float di = rsqrtf((float)d + 1.0f);
    dinv[i] = di;
    float s = z[i] * di;
    zs[i]   = s;
    accR[i] = s;   // self-loop seed in replica 0
#pragma unroll
    for (int r = 1; r < R_ACC; ++r) accR[(size_t)r * Npad + i] = 0.0f;
}

// ---------------- scatter: 4 edges/thread, accR[blk&7][dst] += zs[src] ----------------
__global__ __launch_bounds__(256) void k_scatter(const int* __restrict__ eidx,
                                                 const float* __restrict__ zs,
                                                 float* __restrict__ accR,
                                                 int E, int Npad) {
    float* acc = accR + (size_t)(blockIdx.x & (R_ACC - 1)) * Npad;
    int t = blockIdx.x * blockDim.x + threadIdx.x;
    int e = t * 4;
    if (e + 3 < E) {
        int4 s4 = *(const int4*)(eidx + e);
        int4 d4 = *(const int4*)(eidx + E + e);
        float v0 = zs[s4.x], v1 = zs[s4.y], v2 = zs[s4.z], v3 = zs[s4.w];
        atomicAdd(&acc[d4.x], v0);
        atomicAdd(&acc[d4.y], v1);
        atomicAdd(&acc[d4.z], v2);
        atomicAdd(&acc[d4.w], v3);
    } else {
        for (; e < E; ++e) atomicAdd(&acc[eidx[E + e]], zs[eidx[e]]);
    }
}

// ---------------- final: out = dinv * (sum of replicas) + (b_g.W_out + b_out) ----------------
__global__ __launch_bounds__(256) void k_final(const float* __restrict__ dinv,
                                               const float* __restrict__ accR,
                                               const float* __restrict__ b_g,
                                               const float* __restrict__ W_out,
                                               const float* __restrict__ b_out,
                                               float* __restrict__ out, int N, int Npad) {
    const int lane = threadIdx.x & 63;
    float c = b_g[lane] * W_out[lane];
#pragma unroll
    for (int off = 32; off > 0; off >>= 1)
        c += __shfl_xor(c, off, 64);
    c += b_out[0];

    int i = blockIdx.x * blockDim.x + threadIdx.x;
    if (i >= N) return;
    float a = 0.0f;
#pragma unroll
    for (int r = 0; r < R_ACC; ++r) a += accR[(size_t)r * Npad + i];
    out[i] = fmaf(dinv[i], a, c);
}

// ---------------- launch ----------------

extern "C" void kernel_launch(void* const* d_in, const int* in_sizes, int n_in,
                              void* d_out, int out_size, void* d_ws, size_t ws_size,
                              hipStream_t stream) {
    const float* x     = (const float*)d_in[0];
    const int*   eidx  = (const int*)d_in[1];
    const float* W_in  = (const float*)d_in[2];
    const float* b_in  = (const float*)d_in[3];
    const float* W_g   = (const float*)d_in[4];
    const float* b_g   = (const float*)d_in[5];
    const float* W_out = (const float*)d_in[6];
    const float* b_out = (const float*)d_in[7];
    float* out = (float*)d_out;

    const int N = in_sizes[0] / IN_DIM;   // 100000
    const int E = in_sizes[1] / 2;        // 1600000

    // ws (floats): degR[4*Npad] | z[Npad] | dinv[Npad] | zs[Npad] | accR[8*Npad]
    const int Npad = (N + 63) & ~63;
    int*   degR = (int*)d_ws;
    float* z    = (float*)d_ws + (size_t)R_DEG * Npad;
    float* dinv = z + Npad;
    float* zs   = dinv + Npad;
    float* accR = zs + Npad;

    hipMemsetAsync(degR, 0, (size_t)R_DEG * Npad * sizeof(int), stream);
    k_deg<<<(E / 4 + 255) / 256, 256, 0, stream>>>(eidx + E, degR, E, Npad);
    k_dense<<<(N + 255) / 256, 256, 0, stream>>>(x, W_in, b_in, W_g, W_out, z, N);
    k_dinv<<<(N + 255) / 256, 256, 0, stream>>>(degR, z, dinv, zs, accR, N, Npad);
    k_scatter<<<(E / 4 + 255) / 256, 256, 0, stream>>>(eidx, zs, accR, E, Npad);
    k_final<<<(N + 255) / 256, 256, 0, stream>>>(dinv, accR, b_g, W_out, b_out, out, N, Npad);
}